// Round 1
// baseline (680.875 us; speedup 1.0000x reference)
//
#include <hip/hip_runtime.h>
#include <math.h>

#define THREADS 256

// ---------------------------------------------------------------------------
// Adjacency build: A[g] (64x64), A[dst,src]=1, zero diag. One block per graph.
// ---------------------------------------------------------------------------
__global__ __launch_bounds__(THREADS)
void adj_kernel(const int* __restrict__ eiA, const int* __restrict__ eiB,
                float* __restrict__ Aout)
{
    const int g = blockIdx.x, tid = threadIdx.x;
    const int* eig = (g < 128) ? (eiA + (size_t)g * 1024)
                               : (eiB + (size_t)(g - 128) * 1024);
    __shared__ float Al[4096];
    for (int i = tid; i < 4096; i += THREADS) Al[i] = 0.f;
    __syncthreads();
    for (int e = tid; e < 512; e += THREADS) {
        int s = eig[e], d = eig[512 + e];
        Al[d * 64 + s] = 1.f;   // benign same-value race
    }
    __syncthreads();
    if (tid < 64) Al[tid * 64 + tid] = 0.f;
    __syncthreads();
    for (int i = tid; i < 4096; i += THREADS) Aout[(size_t)g * 4096 + i] = Al[i];
}

// ---------------------------------------------------------------------------
// NNConv: msg[e,o] = sum_i x[src[e],i]*relu(ea[e]*MW[i,o]+MB[i,o]);
// out = relu(segmean_dst(msg) + x@rw + bias).  One block per graph.
// ---------------------------------------------------------------------------
template<int FIN>
__global__ __launch_bounds__(THREADS)
void nnconv_kernel(const float* __restrict__ xA, const float* __restrict__ xB,
                   const int* __restrict__ eiA, const int* __restrict__ eiB,
                   const float* __restrict__ eaA, const float* __restrict__ eaB,
                   const float* __restrict__ mw, const float* __restrict__ mb,
                   const float* __restrict__ rw, const float* __restrict__ bias,
                   float* __restrict__ out)
{
    const int g = blockIdx.x, tid = threadIdx.x;
    const float* xg; const int* eig; const float* eag;
    if (g < 128) {
        xg = xA + (size_t)g * 64 * FIN; eig = eiA + (size_t)g * 1024; eag = eaA + (size_t)g * 512;
    } else {
        int h = g - 128;
        xg = xB + (size_t)h * 64 * FIN; eig = eiB + (size_t)h * 1024; eag = eaB + (size_t)h * 512;
    }

    __shared__ float xl[64 * FIN];
    __shared__ float mwl[FIN * 32];
    __shared__ float mbl[FIN * 32];
    __shared__ int   srcl[512];
    __shared__ int   dstl[512];
    __shared__ float eal[512];
    __shared__ float sums[64 * 32];
    __shared__ float cntl[64];

    for (int i = tid; i < 64 * FIN; i += THREADS) xl[i] = xg[i];
    for (int i = tid; i < FIN * 32; i += THREADS) { mwl[i] = mw[i]; mbl[i] = mb[i]; }
    for (int e = tid; e < 512; e += THREADS) {
        srcl[e] = eig[e]; dstl[e] = eig[512 + e]; eal[e] = eag[e];
    }
    for (int i = tid; i < 2048; i += THREADS) sums[i] = 0.f;
    if (tid < 64) cntl[tid] = 0.f;
    __syncthreads();

    for (int e = tid; e < 512; e += THREADS) atomicAdd(&cntl[dstl[e]], 1.f);
    for (int idx = tid; idx < 512 * 32; idx += THREADS) {
        int e = idx >> 5, o = idx & 31;
        float av = eal[e]; int s = srcl[e];
        float acc = 0.f;
        #pragma unroll 8
        for (int i = 0; i < FIN; i++)
            acc += xl[s * FIN + i] * fmaxf(av * mwl[i * 32 + o] + mbl[i * 32 + o], 0.f);
        atomicAdd(&sums[dstl[e] * 32 + o], acc);
    }
    __syncthreads();

    for (int idx = tid; idx < 2048; idx += THREADS) {
        int n = idx >> 5, o = idx & 31;
        float v = sums[idx] / fmaxf(cntl[n], 1.f);
        float acc = 0.f;
        #pragma unroll 8
        for (int i = 0; i < FIN; i++) acc += xl[n * FIN + i] * rw[i * 32 + o];
        v += acc + bias[o];
        out[(size_t)g * 2048 + idx] = fmaxf(v, 0.f);
    }
}

// ---------------------------------------------------------------------------
// UNet megakernel helpers.  x buffers stride 50, A buffers stride 64.
// ---------------------------------------------------------------------------
__device__ inline void gcn_dev(int n, int cin, int cout,
                               float* x, float* tmp, const float* A, float* dis,
                               const float* __restrict__ W, const float* __restrict__ b,
                               bool do_relu)
{
    const int tid = threadIdx.x;
    // xw = x @ W  (into tmp)
    for (int idx = tid; idx < n * cout; idx += THREADS) {
        int i = idx / cout, o = idx - i * cout;
        float acc = 0.f;
        for (int k = 0; k < cin; k++) acc += x[i * 50 + k] * W[k * cout + o];
        tmp[i * 50 + o] = acc;
    }
    // dis[i] = 1/sqrt(2 + rowsum(A))
    for (int i = tid; i < n; i += THREADS) {
        float s = 2.f;
        for (int j = 0; j < n; j++) s += A[i * 64 + j];
        dis[i] = (s > 0.f) ? (1.0f / sqrtf(s)) : 0.f;
    }
    __syncthreads();
    // y = dis[i] * xw
    for (int idx = tid; idx < n * cout; idx += THREADS) {
        int i = idx / cout, o = idx - i * cout;
        tmp[i * 50 + o] *= dis[i];
    }
    __syncthreads();
    // out[i,o] = dis[i]*(sum_j A[i,j]*y[j,o] + 2*y[i,o]) + b[o]
    for (int idx = tid; idx < n * cout; idx += THREADS) {
        int i = idx / cout, o = idx - i * cout;
        float acc = 2.f * tmp[i * 50 + o];
        for (int j = 0; j < n; j++) acc += A[i * 64 + j] * tmp[j * 50 + o];
        float v = dis[i] * acc + b[o];
        if (do_relu) v = fmaxf(v, 0.f);
        x[i * 50 + o] = v;
    }
    __syncthreads();
}

// A2 = (A+I)@(A+I) * (1-I); relies on diag(A)==0 (holds throughout)
__device__ inline void augment_dev(int n, const float* A, float* A2)
{
    const int tid = threadIdx.x;
    for (int idx = tid; idx < n * n; idx += THREADS) {
        int i = idx / n, j = idx - i * n;
        float acc = 2.f * A[i * 64 + j];
        for (int k = 0; k < n; k++) acc += A[i * 64 + k] * A[k * 64 + j];
        A2[i * 64 + j] = (i == j) ? 0.f : acc;
    }
    __syncthreads();
}

__device__ inline void pool_dev(int n, int k, const float* __restrict__ w,
                                const float* x, float* xnew,
                                const float* A, float* Anew,
                                int* perm, float* svals, float* scr)
{
    const int tid = threadIdx.x;
    // ||w|| (redundant per-thread, cheap; values cached in L1)
    float wn = 0.f;
    for (int q = 0; q < 50; q++) { float t = w[q]; wn += t * t; }
    wn = sqrtf(wn);
    // scores
    for (int i = tid; i < n; i += THREADS) {
        float acc = 0.f;
        for (int q = 0; q < 50; q++) acc += x[i * 50 + q] * w[q];
        scr[i] = tanhf(acc / wn);
    }
    __syncthreads();
    // top-k on wave 0 (stable: ties -> lower index), butterfly argmax
    if (tid < 64) {
        float sj = (tid < n) ? scr[tid] : -1e30f;
        for (int t = 0; t < k; t++) {
            float rv = sj; int ri = tid;
            for (int m = 1; m < 64; m <<= 1) {
                float ov = __shfl_xor(rv, m);
                int   oi = __shfl_xor(ri, m);
                if (ov > rv || (ov == rv && oi < ri)) { rv = ov; ri = oi; }
            }
            if (tid == 0) { perm[t] = ri; svals[t] = rv; }
            if (tid == ri) sj = -1e30f;
        }
    }
    __syncthreads();
    // gather x and A
    for (int idx = tid; idx < k * 50; idx += THREADS) {
        int t = idx / 50, q = idx - t * 50;
        xnew[t * 50 + q] = x[perm[t] * 50 + q] * svals[t];
    }
    for (int idx = tid; idx < k * k; idx += THREADS) {
        int t = idx / k, u = idx - t * k;
        Anew[t * 64 + u] = A[perm[t] * 64 + perm[u]];
    }
    __syncthreads();
}

// ---------------------------------------------------------------------------
// UNet megakernel: one block per graph, full down/up path in LDS.
// ---------------------------------------------------------------------------
__global__ __launch_bounds__(THREADS)
void unet_kernel(const float* __restrict__ xin, const float* __restrict__ Aglob,
                 const float* __restrict__ dw0, const float* __restrict__ db0,
                 const float* __restrict__ dws, const float* __restrict__ dbs,
                 const float* __restrict__ pws,
                 const float* __restrict__ uws, const float* __restrict__ ubs,
                 const float* __restrict__ uwl, const float* __restrict__ ubl,
                 float* __restrict__ ws_xs, float* __restrict__ ws_As,
                 int* __restrict__ ws_perm,
                 float* __restrict__ outp, int mean_mode)
{
    const int g = blockIdx.x, tid = threadIdx.x;
    __shared__ float Aa[4096], Ab[4096];
    __shared__ float xa[3200], xb[3200];
    __shared__ float dis[64];
    __shared__ float svals[64];
    __shared__ int   perm[64];

    float *Acur = Aa, *Aalt = Ab, *xcur = xa, *xalt = xb;

    // load x (64x32 -> stride 50) and A
    const float* xg = xin + (size_t)g * 2048;
    for (int idx = tid; idx < 2048; idx += THREADS) {
        int i = idx >> 5, kk = idx & 31;
        xcur[i * 50 + kk] = xg[idx];
    }
    const float* Ag = Aglob + (size_t)g * 4096;
    for (int idx = tid; idx < 4096; idx += THREADS) Acur[idx] = Ag[idx];
    __syncthreads();

    gcn_dev(64, 32, 50, xcur, xalt, Acur, dis, dw0, db0, true);

    float* xs_g = ws_xs + (size_t)g * 3 * 3200;
    for (int idx = tid; idx < 3200; idx += THREADS) xs_g[idx] = xcur[idx];
    // (next write to this buffer is far behind multiple barriers)

    const int ns[4] = {64, 52, 42, 34};
    for (int lvl = 0; lvl < 3; lvl++) {
        int n = ns[lvl], kk = ns[lvl + 1];
        augment_dev(n, Acur, Aalt);
        { float* t = Acur; Acur = Aalt; Aalt = t; }
        pool_dev(n, kk, pws + lvl * 50, xcur, xalt, Acur, Aalt, perm, svals, dis);
        { float* t = Acur; Acur = Aalt; Aalt = t; t = xcur; xcur = xalt; xalt = t; }
        int* pg = ws_perm + (size_t)g * 192 + lvl * 64;
        for (int t2 = tid; t2 < kk; t2 += THREADS) pg[t2] = perm[t2];
        gcn_dev(kk, 50, 50, xcur, xalt, Acur, dis, dws + lvl * 2500, dbs + lvl * 50, true);
        if (lvl < 2) {
            for (int idx = tid; idx < kk * 50; idx += THREADS)
                xs_g[(lvl + 1) * 3200 + idx] = xcur[idx];
            float* Asg = ws_As + (size_t)g * 8192 + lvl * 4096;
            for (int idx = tid; idx < 4096; idx += THREADS) Asg[idx] = Acur[idx];
        }
    }

    // up path
    for (int i2 = 0; i2 < 3; i2++) {
        int j = 2 - i2;
        int nj = ns[j], kc = ns[j + 1];
        int* pg = ws_perm + (size_t)g * 192 + j * 64;
        for (int t2 = tid; t2 < kc; t2 += THREADS) perm[t2] = pg[t2];
        for (int idx = tid; idx < nj * 50; idx += THREADS) xalt[idx] = xs_g[j * 3200 + idx];
        __syncthreads();
        // x = res + scatter(xcur via perm)  (perm rows unique -> no races)
        for (int idx = tid; idx < kc * 50; idx += THREADS) {
            int t2 = idx / 50, q = idx - t2 * 50;
            xalt[perm[t2] * 50 + q] += xcur[t2 * 50 + q];
        }
        { float* t = xcur; xcur = xalt; xalt = t; }
        const float* Asrc = (j == 0) ? (Aglob + (size_t)g * 4096)
                                     : (ws_As + (size_t)g * 8192 + (size_t)(j - 1) * 4096);
        for (int idx = tid; idx < 4096; idx += THREADS) Acur[idx] = Asrc[idx];
        __syncthreads();
        if (i2 < 2)
            gcn_dev(nj, 50, 50, xcur, xalt, Acur, dis, uws + i2 * 2500, ubs + i2 * 50, true);
        else
            gcn_dev(64, 50, 32, xcur, xalt, Acur, dis, uwl, ubl, false);
    }

    if (mean_mode) {
        // relu then mean over 64 nodes -> (32,)
        for (int o = tid; o < 32; o += THREADS) {
            float acc = 0.f;
            for (int i = 0; i < 64; i++) acc += fmaxf(xcur[i * 50 + o], 0.f);
            outp[(size_t)g * 32 + o] = acc * (1.f / 64.f);
        }
    } else {
        for (int idx = tid; idx < 2048; idx += THREADS) {
            int i = idx >> 5, o = idx & 31;
            outp[(size_t)g * 2048 + idx] = fmaxf(xcur[i * 50 + o], 0.f);
        }
    }
}

// ---------------------------------------------------------------------------
// Head: out[b,h] = relu([r1,jw1,r2,jw2] @ bb_w + bb_b)
// ---------------------------------------------------------------------------
__global__ __launch_bounds__(THREADS)
void head_kernel(const float* __restrict__ r,
                 const float* __restrict__ jw1, const float* __restrict__ jw2,
                 const float* __restrict__ bw, const float* __restrict__ bb,
                 float* __restrict__ out)
{
    const int b = blockIdx.x, h = threadIdx.x;
    float acc = bb[h];
    const float* r1 = r + (size_t)b * 32;
    const float* r2 = r + (size_t)(128 + b) * 32;
    #pragma unroll
    for (int q = 0; q < 32; q++) acc += r1[q] * bw[q * 256 + h];
    #pragma unroll
    for (int q = 0; q < 16; q++) acc += jw1[b * 16 + q] * bw[(32 + q) * 256 + h];
    #pragma unroll
    for (int q = 0; q < 32; q++) acc += r2[q] * bw[(48 + q) * 256 + h];
    #pragma unroll
    for (int q = 0; q < 16; q++) acc += jw2[b * 16 + q] * bw[(80 + q) * 256 + h];
    out[(size_t)b * 256 + h] = fmaxf(acc, 0.f);
}

// ---------------------------------------------------------------------------
extern "C" void kernel_launch(void* const* d_in, const int* in_sizes, int n_in,
                              void* d_out, int out_size, void* d_ws, size_t ws_size,
                              hipStream_t stream)
{
    const float* x1  = (const float*)d_in[0];
    const int*   ei1 = (const int*)  d_in[1];
    const float* ea1 = (const float*)d_in[2];
    const float* jw1 = (const float*)d_in[3];
    const float* x2  = (const float*)d_in[4];
    const int*   ei2 = (const int*)  d_in[5];
    const float* ea2 = (const float*)d_in[6];
    const float* jw2 = (const float*)d_in[7];
    const float* m1w = (const float*)d_in[8];
    const float* m1b = (const float*)d_in[9];
    const float* r1w = (const float*)d_in[10];
    const float* c1b = (const float*)d_in[11];
    const float* m2w = (const float*)d_in[12];
    const float* m2b = (const float*)d_in[13];
    const float* r2w = (const float*)d_in[14];
    const float* c2b = (const float*)d_in[15];
    const float* u1p[9]; for (int i = 0; i < 9; i++) u1p[i] = (const float*)d_in[16 + i];
    const float* u2p[9]; for (int i = 0; i < 9; i++) u2p[i] = (const float*)d_in[25 + i];
    const float* bbw = (const float*)d_in[34];
    const float* bbb = (const float*)d_in[35];

    char* ws = (char*)d_ws;
    size_t off = 0;
    float* A    = (float*)(ws + off); off += 256ull * 4096 * 4;     // adjacency
    float* xc1  = (float*)(ws + off); off += 256ull * 2048 * 4;     // nnconv1 out
    float* xu1  = (float*)(ws + off); off += 256ull * 2048 * 4;     // unet1 out
    float* xc2  = (float*)(ws + off); off += 256ull * 2048 * 4;     // nnconv2 out
    float* rr   = (float*)(ws + off); off += 256ull * 32 * 4;       // unet2 mean
    float* wxs  = (float*)(ws + off); off += 256ull * 3 * 3200 * 4; // skip x
    float* wAs  = (float*)(ws + off); off += 256ull * 2 * 4096 * 4; // skip A
    int*   wpm  = (int*)  (ws + off); off += 256ull * 3 * 64 * 4;   // perms
    (void)ws_size; (void)in_sizes; (void)n_in; (void)out_size;

    adj_kernel<<<256, THREADS, 0, stream>>>(ei1, ei2, A);
    nnconv_kernel<64><<<256, THREADS, 0, stream>>>(x1, x2, ei1, ei2, ea1, ea2,
                                                   m1w, m1b, r1w, c1b, xc1);
    unet_kernel<<<256, THREADS, 0, stream>>>(xc1, A,
        u1p[0], u1p[1], u1p[2], u1p[3], u1p[4], u1p[5], u1p[6], u1p[7], u1p[8],
        wxs, wAs, wpm, xu1, 0);
    nnconv_kernel<32><<<256, THREADS, 0, stream>>>(xu1, xu1 + 128ull * 2048,
                                                   ei1, ei2, ea1, ea2,
                                                   m2w, m2b, r2w, c2b, xc2);
    unet_kernel<<<256, THREADS, 0, stream>>>(xc2, A,
        u2p[0], u2p[1], u2p[2], u2p[3], u2p[4], u2p[5], u2p[6], u2p[7], u2p[8],
        wxs, wAs, wpm, rr, 1);
    head_kernel<<<128, THREADS, 0, stream>>>(rr, jw1, jw2, bbw, bbb, (float*)d_out);
}

// Round 2
// 358.444 us; speedup vs baseline: 1.8995x; 1.8995x over previous
//
#include <hip/hip_runtime.h>
#include <math.h>

#define UT 1024
#define XS 52      // x-buffer row stride (even, mult of 4 -> 16B-aligned strips)
#define ASTR 65    // A-buffer row stride (odd -> conflict-free column access)

__device__ __forceinline__ float wred16(float v) {
    v += __shfl_xor(v, 8); v += __shfl_xor(v, 4);
    v += __shfl_xor(v, 2); v += __shfl_xor(v, 1);
    return v;
}

// ---------------------------------------------------------------------------
// Adjacency build: A[g] (64x64), A[dst,src]=1, zero diag. One block per graph.
// ---------------------------------------------------------------------------
__global__ __launch_bounds__(256)
void adj_kernel(const int* __restrict__ eiA, const int* __restrict__ eiB,
                float* __restrict__ Aout)
{
    const int g = blockIdx.x, tid = threadIdx.x;
    const int* eig = (g < 128) ? (eiA + (size_t)g * 1024)
                               : (eiB + (size_t)(g - 128) * 1024);
    __shared__ float Al[4096];
    for (int i = tid; i < 4096; i += 256) Al[i] = 0.f;
    __syncthreads();
    for (int e = tid; e < 512; e += 256) {
        int s = eig[e], d = eig[512 + e];
        Al[d * 64 + s] = 1.f;   // benign same-value race
    }
    __syncthreads();
    if (tid < 64) Al[tid * 64 + tid] = 0.f;
    __syncthreads();
    for (int i = tid; i < 4096; i += 256) Aout[(size_t)g * 4096 + i] = Al[i];
}

// ---------------------------------------------------------------------------
// NNConv, 1024 threads: weights-in-registers edge loop.
// msg[e,o] = sum_i x[src,i]*relu(ea*MW[i,o]+MB[i,o]);
// out = relu(segmean_dst(msg) + x@rw + bias)
// ---------------------------------------------------------------------------
template<int FIN>
__global__ __launch_bounds__(UT)
void nnconv_kernel(const float* __restrict__ xA, const float* __restrict__ xB,
                   const int* __restrict__ eiA, const int* __restrict__ eiB,
                   const float* __restrict__ eaA, const float* __restrict__ eaB,
                   const float* __restrict__ mw, const float* __restrict__ mb,
                   const float* __restrict__ rw, const float* __restrict__ bias,
                   float* __restrict__ out)
{
    constexpr int ICN = FIN / 16;            // i-chunks of 16
    constexpr int ERN = UT / (32 * ICN);     // edge groups
    constexpr int EPT = 512 / ERN;           // edges per thread
    const int g = blockIdx.x, tid = threadIdx.x;
    const float* xg; const int* eig; const float* eag;
    if (g < 128) {
        xg = xA + (size_t)g * 64 * FIN; eig = eiA + (size_t)g * 1024; eag = eaA + (size_t)g * 512;
    } else {
        int h = g - 128;
        xg = xB + (size_t)h * 64 * FIN; eig = eiB + (size_t)h * 1024; eag = eaB + (size_t)h * 512;
    }

    __shared__ __align__(16) float xl[64 * FIN];
    __shared__ __align__(16) float mwl[FIN * 32];
    __shared__ __align__(16) float mbl[FIN * 32];
    __shared__ __align__(16) float rwl[FIN * 32];
    __shared__ __align__(16) float sums[64 * 32];
    __shared__ int   srcl[512];
    __shared__ int   dstl[512];
    __shared__ float eal[512];
    __shared__ float cntl[64];

    for (int i = tid; i < 64 * FIN; i += UT) xl[i] = xg[i];
    for (int i = tid; i < FIN * 32; i += UT) { mwl[i] = mw[i]; mbl[i] = mb[i]; rwl[i] = rw[i]; }
    for (int e = tid; e < 512; e += UT) {
        srcl[e] = eig[e]; dstl[e] = eig[512 + e]; eal[e] = eag[e];
    }
    for (int i = tid; i < 2048; i += UT) sums[i] = 0.f;
    if (tid < 64) cntl[tid] = 0.f;
    __syncthreads();

    const int o = tid & 31, ic = (tid >> 5) & (ICN - 1), er = tid / (32 * ICN);
    float mwr[16], mbr[16];
    #pragma unroll
    for (int z = 0; z < 16; z++) {
        mwr[z] = mwl[(ic * 16 + z) * 32 + o];
        mbr[z] = mbl[(ic * 16 + z) * 32 + o];
    }
    for (int e = tid; e < 512; e += UT) atomicAdd(&cntl[dstl[e]], 1.f);

    for (int e = er * EPT; e < er * EPT + EPT; e++) {
        int s = srcl[e]; int d = dstl[e]; float av = eal[e];
        float acc = 0.f;
        #pragma unroll
        for (int z = 0; z < 16; z += 4) {
            float4 xv = *(const float4*)&xl[s * FIN + ic * 16 + z];
            acc += xv.x * fmaxf(fmaf(av, mwr[z + 0], mbr[z + 0]), 0.f);
            acc += xv.y * fmaxf(fmaf(av, mwr[z + 1], mbr[z + 1]), 0.f);
            acc += xv.z * fmaxf(fmaf(av, mwr[z + 2], mbr[z + 2]), 0.f);
            acc += xv.w * fmaxf(fmaf(av, mwr[z + 3], mbr[z + 3]), 0.f);
        }
        acc += __shfl_down(acc, 32);            // combine ic pairs in-wave
        if ((tid & 32) == 0) atomicAdd(&sums[d * 32 + o], acc);
    }
    __syncthreads();

    // epilogue: out = relu(sums/max(cnt,1) + x@rw + bias)
    for (int it = tid; it < 512; it += UT) {   // 64 nodes x 8 strips
        int nn = it >> 3, o0 = (it & 7) * 4;
        float a0 = 0.f, a1 = 0.f, a2 = 0.f, a3 = 0.f;
        for (int i = 0; i < FIN; i++) {
            float xv = xl[nn * FIN + i];
            float4 w = *(const float4*)&rwl[i * 32 + o0];
            a0 = fmaf(xv, w.x, a0); a1 = fmaf(xv, w.y, a1);
            a2 = fmaf(xv, w.z, a2); a3 = fmaf(xv, w.w, a3);
        }
        float inv = 1.0f / fmaxf(cntl[nn], 1.f);
        float4 sv = *(const float4*)&sums[nn * 32 + o0];
        float4 bv = *(const float4*)&bias[o0];
        float4 r;
        r.x = fmaxf(sv.x * inv + a0 + bv.x, 0.f);
        r.y = fmaxf(sv.y * inv + a1 + bv.y, 0.f);
        r.z = fmaxf(sv.z * inv + a2 + bv.z, 0.f);
        r.w = fmaxf(sv.w * inv + a3 + bv.w, 0.f);
        *(float4*)&out[(size_t)g * 2048 + nn * 32 + o0] = r;
    }
}

// ---------------------------------------------------------------------------
// GCN on LDS buffers. x in/out stride XS (in-place), tmp scratch stride XS,
// A stride ASTR, Wl = scratch (dead A buffer) for staged weights (+bias row 50).
// out[i,o] = dis[i]*(sum_j A[i,j]*dis[j]*(xW)[j,o] + 2*dis[i]*(xW)[i,o]) + b[o]
// n must be even.
// ---------------------------------------------------------------------------
__device__ __forceinline__ void gcn_u(int n, int cin, int cout,
    float* __restrict__ x, float* __restrict__ tmp,
    const float* __restrict__ A, float* __restrict__ Wl,
    float* __restrict__ dis,
    const float* __restrict__ Wg, const float* __restrict__ bg, bool relu)
{
    const int tid = threadIdx.x;
    const int nso = (cout + 3) >> 2;     // output strips
    // stage W (+bias row 50), compute dis
    for (int idx = tid; idx < 51 * 52; idx += UT) {
        int r = idx / 52, c = idx - r * 52;
        float v = 0.f;
        if (r < cin && c < cout) v = Wg[r * cout + c];
        else if (r == 50 && c < cout) v = bg[c];
        Wl[idx] = v;
    }
    {
        int r = tid >> 4, l = tid & 15;
        float s = 0.f;
        if (r < n) for (int j = l; j < n; j += 16) s += A[r * ASTR + j];
        s = wred16(s);
        if (l == 0 && r < n) dis[r] = 1.0f / sqrtf(2.0f + s);
    }
    __syncthreads();
    // tmp[i,o] = dis[i] * (x@W)[i,o]   (2 rows x 4-o strip per thread)
    int nr2 = n >> 1;
    for (int it = tid; it < nr2 * nso; it += UT) {
        int i0 = (it / nso) * 2, o0 = (it - (it / nso) * nso) * 4;
        float a0=0,a1=0,a2=0,a3=0, b0=0,b1=0,b2=0,b3=0;
        for (int k = 0; k < cin; k++) {
            float4 w = *(const float4*)&Wl[k * 52 + o0];
            float x0 = x[i0 * XS + k], x1 = x[(i0 + 1) * XS + k];
            a0 = fmaf(x0, w.x, a0); a1 = fmaf(x0, w.y, a1);
            a2 = fmaf(x0, w.z, a2); a3 = fmaf(x0, w.w, a3);
            b0 = fmaf(x1, w.x, b0); b1 = fmaf(x1, w.y, b1);
            b2 = fmaf(x1, w.z, b2); b3 = fmaf(x1, w.w, b3);
        }
        float d0 = dis[i0], d1 = dis[i0 + 1];
        float4 t0; t0.x = a0*d0; t0.y = a1*d0; t0.z = a2*d0; t0.w = a3*d0;
        float4 t1; t1.x = b0*d1; t1.y = b1*d1; t1.z = b2*d1; t1.w = b3*d1;
        *(float4*)&tmp[i0 * XS + o0] = t0;
        *(float4*)&tmp[(i0 + 1) * XS + o0] = t1;
    }
    __syncthreads();
    // x[i,o] = dis[i]*(A[i,:]@tmp[:,o] + 2*tmp[i,o]) + b[o]
    for (int it = tid; it < nr2 * nso; it += UT) {
        int i0 = (it / nso) * 2, o0 = (it - (it / nso) * nso) * 4;
        float a0=0,a1=0,a2=0,a3=0, b0=0,b1=0,b2=0,b3=0;
        for (int j = 0; j < n; j++) {
            float4 t = *(const float4*)&tmp[j * XS + o0];
            float av0 = A[i0 * ASTR + j], av1 = A[(i0 + 1) * ASTR + j];
            a0 = fmaf(av0, t.x, a0); a1 = fmaf(av0, t.y, a1);
            a2 = fmaf(av0, t.z, a2); a3 = fmaf(av0, t.w, a3);
            b0 = fmaf(av1, t.x, b0); b1 = fmaf(av1, t.y, b1);
            b2 = fmaf(av1, t.z, b2); b3 = fmaf(av1, t.w, b3);
        }
        float4 bias = *(const float4*)&Wl[50 * 52 + o0];
        float4 s0 = *(const float4*)&tmp[i0 * XS + o0];
        float4 s1 = *(const float4*)&tmp[(i0 + 1) * XS + o0];
        float d0 = dis[i0], d1 = dis[i0 + 1];
        float4 r0, r1;
        r0.x = fmaf(d0, a0 + 2.f*s0.x, bias.x); r0.y = fmaf(d0, a1 + 2.f*s0.y, bias.y);
        r0.z = fmaf(d0, a2 + 2.f*s0.z, bias.z); r0.w = fmaf(d0, a3 + 2.f*s0.w, bias.w);
        r1.x = fmaf(d1, b0 + 2.f*s1.x, bias.x); r1.y = fmaf(d1, b1 + 2.f*s1.y, bias.y);
        r1.z = fmaf(d1, b2 + 2.f*s1.z, bias.z); r1.w = fmaf(d1, b3 + 2.f*s1.w, bias.w);
        if (relu) {
            r0.x = fmaxf(r0.x, 0.f); r0.y = fmaxf(r0.y, 0.f);
            r0.z = fmaxf(r0.z, 0.f); r0.w = fmaxf(r0.w, 0.f);
            r1.x = fmaxf(r1.x, 0.f); r1.y = fmaxf(r1.y, 0.f);
            r1.z = fmaxf(r1.z, 0.f); r1.w = fmaxf(r1.w, 0.f);
        }
        *(float4*)&x[i0 * XS + o0] = r0;
        *(float4*)&x[(i0 + 1) * XS + o0] = r1;
    }
    __syncthreads();
}

// ---------------------------------------------------------------------------
// UNet megakernel, 1024 threads, one block per graph.
// ---------------------------------------------------------------------------
__global__ __launch_bounds__(UT)
void unet_kernel(const float* __restrict__ xin, const float* __restrict__ Aglob,
                 const float* __restrict__ dw0, const float* __restrict__ db0,
                 const float* __restrict__ dws, const float* __restrict__ dbs,
                 const float* __restrict__ pws,
                 const float* __restrict__ uws, const float* __restrict__ ubs,
                 const float* __restrict__ uwl, const float* __restrict__ ubl,
                 float* __restrict__ ws_xs, float* __restrict__ ws_As,
                 float* __restrict__ outp, int mean_mode)
{
    const int g = blockIdx.x, tid = threadIdx.x;
    __shared__ __align__(16) float Aa[64 * ASTR];
    __shared__ __align__(16) float Ab[64 * ASTR];
    __shared__ __align__(16) float x0c[64 * XS];
    __shared__ __align__(16) float x1c[64 * XS];
    __shared__ float scr[64];
    __shared__ float dis[64];
    __shared__ float svals[64];
    __shared__ int   permL[192];

    float *pA = Aa, *pF = Ab, *px = x0c, *pt_ = x1c;
    float* xs_g = ws_xs + (size_t)g * 9984;   // 3 x 3328
    float* as_g = ws_As + (size_t)g * 6144;   // A1(3380) + A2(2730)
    const float* Ag_g = Aglob + (size_t)g * 4096;
    const int nsz[4] = {64, 52, 42, 34};

    // initial loads
    {
        const float* xg = xin + (size_t)g * 2048;
        for (int idx = tid; idx < 512; idx += UT) {
            int i = idx >> 3, o0 = (idx & 7) * 4;
            *(float4*)&px[i * XS + o0] = *(const float4*)&xg[i * 32 + o0];
        }
        for (int idx = tid; idx < 4096; idx += UT)
            pA[(idx >> 6) * ASTR + (idx & 63)] = Ag_g[idx];
    }
    __syncthreads();

    gcn_u(64, 32, 50, px, pt_, pA, pF, dis, dw0, db0, true);

    // ---- down path ----
    for (int lvl = 0; lvl < 3; lvl++) {
        int n = nsz[lvl], kk = nsz[lvl + 1];
        const float* wg = pws + lvl * 50;
        int* perm = permL + lvl * 64;
        // scores + skip saves
        {
            int r = tid >> 4, l = tid & 15;
            float s = 0.f, wn = 0.f;
            for (int q = l; q < 50; q += 16) {
                float wv = wg[q];
                wn = fmaf(wv, wv, wn);
                s = fmaf(px[r * XS + q], wv, s);
            }
            s = wred16(s); wn = wred16(wn);
            if (l == 0 && r < n) scr[r] = tanhf(s / sqrtf(wn));
        }
        {
            float* xd = xs_g + lvl * 3328;
            for (int idx = tid; idx < 3328; idx += UT) xd[idx] = px[idx];
            if (lvl == 1) for (int idx = tid; idx < 52 * ASTR; idx += UT) as_g[idx] = pA[idx];
            if (lvl == 2) for (int idx = tid; idx < 42 * ASTR; idx += UT) as_g[3380 + idx] = pA[idx];
        }
        __syncthreads();
        // bitonic top-k on wave 0 (desc score, asc index — lax.top_k semantics)
        if (tid < 64) {
            float v = (tid < n) ? scr[tid] : -2.0f;
            int id = tid;
            for (int sz = 2; sz <= 64; sz <<= 1)
                for (int st = sz >> 1; st > 0; st >>= 1) {
                    float ov = __shfl_xor(v, st);
                    int oi = __shfl_xor(id, st);
                    bool up = ((tid & sz) == 0);
                    bool lower = ((tid & st) == 0);
                    bool less = (v > ov) || (v == ov && id < oi);
                    bool keep = (up == lower) ? less : !less;
                    if (!keep) { v = ov; id = oi; }
                }
            if (tid < kk) { perm[tid] = id; svals[tid] = v; }
        }
        __syncthreads();
        // Ag = Aold[:, perm] into pt_ (zero-padded cols), gather x->regs
        for (int idx = tid; idx < n * 13; idx += UT) {
            int m = idx / 13, u0 = (idx - (idx / 13) * 13) * 4;
            float4 gv;
            gv.x = (u0 + 0 < kk) ? pA[m * ASTR + perm[u0 + 0]] : 0.f;
            gv.y = (u0 + 1 < kk) ? pA[m * ASTR + perm[u0 + 1]] : 0.f;
            gv.z = (u0 + 2 < kk) ? pA[m * ASTR + perm[u0 + 2]] : 0.f;
            gv.w = (u0 + 3 < kk) ? pA[m * ASTR + perm[u0 + 3]] : 0.f;
            *(float4*)&pt_[m * XS + u0] = gv;
        }
        float gx0=0, gx1=0, gx2=0, gx3=0; int gdst = -1;
        if (tid < kk * 13) {
            int t = tid / 13, q0 = (tid - t * 13) * 4;
            float sv = svals[t]; int p = perm[t];
            gx0 = px[p * XS + q0 + 0] * sv; gx1 = px[p * XS + q0 + 1] * sv;
            gx2 = px[p * XS + q0 + 2] * sv; gx3 = px[p * XS + q0 + 3] * sv;
            gdst = t * XS + q0;
        }
        __syncthreads();
        // Anew[t,u] = 2*Ag[pt,u] + sum_m Aold[pt,m]*Ag[m,u]; x writeback
        if (gdst >= 0) {
            px[gdst] = gx0; px[gdst + 1] = gx1; px[gdst + 2] = gx2; px[gdst + 3] = gx3;
        }
        int nt2 = kk >> 1, nst = (kk + 3) >> 2;
        for (int it = tid; it < nt2 * nst; it += UT) {
            int t0 = (it / nst) * 2, u0 = (it - (it / nst) * nst) * 4;
            int p0 = perm[t0], p1 = perm[t0 + 1];
            float a0=0,a1=0,a2=0,a3=0, b0=0,b1=0,b2=0,b3=0;
            for (int m = 0; m < n; m++) {
                float4 gv = *(const float4*)&pt_[m * XS + u0];
                float q0v = pA[p0 * ASTR + m], q1v = pA[p1 * ASTR + m];
                a0 = fmaf(q0v, gv.x, a0); a1 = fmaf(q0v, gv.y, a1);
                a2 = fmaf(q0v, gv.z, a2); a3 = fmaf(q0v, gv.w, a3);
                b0 = fmaf(q1v, gv.x, b0); b1 = fmaf(q1v, gv.y, b1);
                b2 = fmaf(q1v, gv.z, b2); b3 = fmaf(q1v, gv.w, b3);
            }
            float4 g0 = *(const float4*)&pt_[p0 * XS + u0];
            float4 g1 = *(const float4*)&pt_[p1 * XS + u0];
            float v;
            v = a0 + 2.f*g0.x; pF[t0*ASTR + u0+0] = (u0+0 == t0) ? 0.f : v;
            v = a1 + 2.f*g0.y; pF[t0*ASTR + u0+1] = (u0+1 == t0) ? 0.f : v;
            v = a2 + 2.f*g0.z; pF[t0*ASTR + u0+2] = (u0+2 == t0) ? 0.f : v;
            v = a3 + 2.f*g0.w; pF[t0*ASTR + u0+3] = (u0+3 == t0) ? 0.f : v;
            v = b0 + 2.f*g1.x; pF[(t0+1)*ASTR + u0+0] = (u0+0 == t0+1) ? 0.f : v;
            v = b1 + 2.f*g1.y; pF[(t0+1)*ASTR + u0+1] = (u0+1 == t0+1) ? 0.f : v;
            v = b2 + 2.f*g1.z; pF[(t0+1)*ASTR + u0+2] = (u0+2 == t0+1) ? 0.f : v;
            v = b3 + 2.f*g1.w; pF[(t0+1)*ASTR + u0+3] = (u0+3 == t0+1) ? 0.f : v;
        }
        __syncthreads();
        gcn_u(kk, 50, 50, px, pt_, pF, pA, dis, dws + lvl * 2500, dbs + lvl * 50, true);
        { float* t = pA; pA = pF; pF = t; }
    }

    // ---- up path ----
    for (int i2 = 0; i2 < 3; i2++) {
        int j = 2 - i2;
        int nj = nsz[j], kc = nsz[j + 1];
        {   // load residual into pt_, load A into pF
            const float* resg = xs_g + j * 3328;
            for (int idx = tid; idx < 3328; idx += UT) pt_[idx] = resg[idx];
            if (j == 0) {
                for (int idx = tid; idx < 4096; idx += UT)
                    pF[(idx >> 6) * ASTR + (idx & 63)] = Ag_g[idx];
            } else if (j == 1) {
                for (int idx = tid; idx < 52 * ASTR; idx += UT) pF[idx] = as_g[idx];
            } else {
                for (int idx = tid; idx < 42 * ASTR; idx += UT) pF[idx] = as_g[3380 + idx];
            }
        }
        __syncthreads();
        const int* perm = permL + j * 64;
        for (int it = tid; it < kc * 13; it += UT) {
            int t = it / 13, q0 = (it - (it / 13) * 13) * 4;
            int p = perm[t];
            pt_[p * XS + q0 + 0] += px[t * XS + q0 + 0];
            pt_[p * XS + q0 + 1] += px[t * XS + q0 + 1];
            pt_[p * XS + q0 + 2] += px[t * XS + q0 + 2];
            pt_[p * XS + q0 + 3] += px[t * XS + q0 + 3];
        }
        __syncthreads();
        if (i2 < 2)
            gcn_u(nj, 50, 50, pt_, px, pF, pA, dis, uws + i2 * 2500, ubs + i2 * 50, true);
        else
            gcn_u(64, 50, 32, pt_, px, pF, pA, dis, uwl, ubl, false);
        { float* t2 = px; px = pt_; pt_ = t2; }
        { float* t2 = pA; pA = pF; pF = t2; }
    }

    // epilogue
    if (mean_mode) {
        int r = tid >> 4, l = tid & 15;     // whole-wave uniform r<32 split
        if (r < 32) {
            float s = 0.f;
            for (int i = l; i < 64; i += 16) s += fmaxf(px[i * XS + r], 0.f);
            s = wred16(s);
            if (l == 0) outp[(size_t)g * 32 + r] = s * (1.0f / 64.0f);
        }
    } else {
        float* og = outp + (size_t)g * 2048;
        for (int idx = tid; idx < 512; idx += UT) {
            int i = idx >> 3, o0 = (idx & 7) * 4;
            float4 vv = *(const float4*)&px[i * XS + o0];
            vv.x = fmaxf(vv.x, 0.f); vv.y = fmaxf(vv.y, 0.f);
            vv.z = fmaxf(vv.z, 0.f); vv.w = fmaxf(vv.w, 0.f);
            *(float4*)&og[i * 32 + o0] = vv;
        }
    }
}

// ---------------------------------------------------------------------------
// Head: out[b,h] = relu([r1,jw1,r2,jw2] @ bb_w + bb_b)
// ---------------------------------------------------------------------------
__global__ __launch_bounds__(256)
void head_kernel(const float* __restrict__ r,
                 const float* __restrict__ jw1, const float* __restrict__ jw2,
                 const float* __restrict__ bw, const float* __restrict__ bb,
                 float* __restrict__ out)
{
    const int b = blockIdx.x, h = threadIdx.x;
    float acc = bb[h];
    const float* r1 = r + (size_t)b * 32;
    const float* r2 = r + (size_t)(128 + b) * 32;
    #pragma unroll
    for (int q = 0; q < 32; q++) acc += r1[q] * bw[q * 256 + h];
    #pragma unroll
    for (int q = 0; q < 16; q++) acc += jw1[b * 16 + q] * bw[(32 + q) * 256 + h];
    #pragma unroll
    for (int q = 0; q < 32; q++) acc += r2[q] * bw[(48 + q) * 256 + h];
    #pragma unroll
    for (int q = 0; q < 16; q++) acc += jw2[b * 16 + q] * bw[(80 + q) * 256 + h];
    out[(size_t)b * 256 + h] = fmaxf(acc, 0.f);
}

// ---------------------------------------------------------------------------
extern "C" void kernel_launch(void* const* d_in, const int* in_sizes, int n_in,
                              void* d_out, int out_size, void* d_ws, size_t ws_size,
                              hipStream_t stream)
{
    const float* x1  = (const float*)d_in[0];
    const int*   ei1 = (const int*)  d_in[1];
    const float* ea1 = (const float*)d_in[2];
    const float* jw1 = (const float*)d_in[3];
    const float* x2  = (const float*)d_in[4];
    const int*   ei2 = (const int*)  d_in[5];
    const float* ea2 = (const float*)d_in[6];
    const float* jw2 = (const float*)d_in[7];
    const float* m1w = (const float*)d_in[8];
    const float* m1b = (const float*)d_in[9];
    const float* r1w = (const float*)d_in[10];
    const float* c1b = (const float*)d_in[11];
    const float* m2w = (const float*)d_in[12];
    const float* m2b = (const float*)d_in[13];
    const float* r2w = (const float*)d_in[14];
    const float* c2b = (const float*)d_in[15];
    const float* u1p[9]; for (int i = 0; i < 9; i++) u1p[i] = (const float*)d_in[16 + i];
    const float* u2p[9]; for (int i = 0; i < 9; i++) u2p[i] = (const float*)d_in[25 + i];
    const float* bbw = (const float*)d_in[34];
    const float* bbb = (const float*)d_in[35];

    char* ws = (char*)d_ws;
    size_t off = 0;
    float* A    = (float*)(ws + off); off += 256ull * 4096 * 4;     // adjacency
    float* xc1  = (float*)(ws + off); off += 256ull * 2048 * 4;     // nnconv1 out
    float* xu1  = (float*)(ws + off); off += 256ull * 2048 * 4;     // unet1 out
    float* xc2  = (float*)(ws + off); off += 256ull * 2048 * 4;     // nnconv2 out
    float* rr   = (float*)(ws + off); off += 256ull * 32 * 4;       // unet2 mean
    float* wxs  = (float*)(ws + off); off += 256ull * 9984 * 4;     // skip x
    float* wAs  = (float*)(ws + off); off += 256ull * 6144 * 4;     // skip A
    (void)ws_size; (void)in_sizes; (void)n_in; (void)out_size;

    adj_kernel<<<256, 256, 0, stream>>>(ei1, ei2, A);
    nnconv_kernel<64><<<256, UT, 0, stream>>>(x1, x2, ei1, ei2, ea1, ea2,
                                              m1w, m1b, r1w, c1b, xc1);
    unet_kernel<<<256, UT, 0, stream>>>(xc1, A,
        u1p[0], u1p[1], u1p[2], u1p[3], u1p[4], u1p[5], u1p[6], u1p[7], u1p[8],
        wxs, wAs, xu1, 0);
    nnconv_kernel<32><<<256, UT, 0, stream>>>(xu1, xu1 + 128ull * 2048,
                                              ei1, ei2, ea1, ea2,
                                              m2w, m2b, r2w, c2b, xc2);
    unet_kernel<<<256, UT, 0, stream>>>(xc2, A,
        u2p[0], u2p[1], u2p[2], u2p[3], u2p[4], u2p[5], u2p[6], u2p[7], u2p[8],
        wxs, wAs, rr, 1);
    head_kernel<<<128, 256, 0, stream>>>(rr, jw1, jw2, bbw, bbb, (float*)d_out);
}